// Round 10
// baseline (279.670 us; speedup 1.0000x reference)
//
#include <hip/hip_runtime.h>
#include <math.h>

#define NEG_SLOPE 0.2f
#define EPS 1e-16f
#define PPART 256          // scatter blocks (in hetero K1)
#define BMAX 512           // max buckets (B = ceil(N/256) = 391)
#define BSTRIDE 6144       // part[] slots per bucket (max bucket ~3.7k)
#define GAGG_BLOCKS 2048   // agg kernel grid

// ---- bf16 helpers ----
__device__ __forceinline__ unsigned short f2bf(float f) {
    unsigned int x = __float_as_uint(f);
    unsigned int r = (x + 0x7FFFu + ((x >> 16) & 1u)) >> 16;
    return (unsigned short)r;
}
__device__ __forceinline__ float bf2f(unsigned short u) {
    return __uint_as_float(((unsigned int)u) << 16);
}

// ============================================================
// GEMM body: H(bf16) = X @ W ; Ss = H.a_src, Sd = H.a_dst.
// X is fp32 (xbf16=0) or bf16 (xbf16=1).
// smem: Ws 4096 f + Xs 64*XPAD f (50176 B)
// ============================================================
#define XPAD 132
__device__ __forceinline__ void gemm_body(
    char* smem, int bid, int t,
    const void* __restrict__ Xv, int xbf16, const float* __restrict__ W,
    const float* __restrict__ asrc, const float* __restrict__ adst,
    unsigned short* __restrict__ Hb, float* __restrict__ Ss, float* __restrict__ Sd, int N)
{
    float* Ws = (float*)smem;            // 64*64
    float* Xs = Ws + 4096;               // 64*XPAD
    int row0 = bid * 128;

    {
        const float4* W4 = (const float4*)W;
        float4* Ws4 = (float4*)Ws;
#pragma unroll
        for (int i = 0; i < 4; ++i) Ws4[i * 256 + t] = W4[i * 256 + t];
    }
    if (!xbf16) {
        const float4* X4 = (const float4*)Xv;
#pragma unroll
        for (int i = 0; i < 8; ++i) {
            int v = i * 256 + t;
            int r = v >> 4;
            int c4 = (v & 15) * 4;
            int grow = row0 + r;
            float4 xv = make_float4(0.f, 0.f, 0.f, 0.f);
            if (grow < N) xv = X4[(size_t)grow * 16 + (c4 >> 2)];
            Xs[(c4 + 0) * XPAD + r] = xv.x;
            Xs[(c4 + 1) * XPAD + r] = xv.y;
            Xs[(c4 + 2) * XPAD + r] = xv.z;
            Xs[(c4 + 3) * XPAD + r] = xv.w;
        }
    } else {
        const uint4* X4 = (const uint4*)Xv;   // 8 bf16 per uint4; row = 8 uint4
#pragma unroll
        for (int i = 0; i < 4; ++i) {
            int v = i * 256 + t;
            int r = v >> 3;                   // 0..127
            int c8 = (v & 7) * 8;             // 0,8,...,56
            int grow = row0 + r;
            uint4 xv = make_uint4(0, 0, 0, 0);
            if (grow < N) xv = X4[(size_t)grow * 8 + (c8 >> 3)];
            Xs[(c8 + 0) * XPAD + r] = bf2f((unsigned short)(xv.x & 0xFFFF));
            Xs[(c8 + 1) * XPAD + r] = bf2f((unsigned short)(xv.x >> 16));
            Xs[(c8 + 2) * XPAD + r] = bf2f((unsigned short)(xv.y & 0xFFFF));
            Xs[(c8 + 3) * XPAD + r] = bf2f((unsigned short)(xv.y >> 16));
            Xs[(c8 + 4) * XPAD + r] = bf2f((unsigned short)(xv.z & 0xFFFF));
            Xs[(c8 + 5) * XPAD + r] = bf2f((unsigned short)(xv.z >> 16));
            Xs[(c8 + 6) * XPAD + r] = bf2f((unsigned short)(xv.w & 0xFFFF));
            Xs[(c8 + 7) * XPAD + r] = bf2f((unsigned short)(xv.w >> 16));
        }
    }
    __syncthreads();

    int cg = t & 7;
    int rg = t >> 3;
    float acc[4][8] = {{0.f}};

#pragma unroll 8
    for (int k = 0; k < 64; ++k) {
        float4 xv = *(const float4*)&Xs[k * XPAD + rg * 4];
        float4 w0 = *(const float4*)&Ws[k * 64 + cg * 8];
        float4 w1 = *(const float4*)&Ws[k * 64 + cg * 8 + 4];
        float xr[4] = {xv.x, xv.y, xv.z, xv.w};
        float wc[8] = {w0.x, w0.y, w0.z, w0.w, w1.x, w1.y, w1.z, w1.w};
#pragma unroll
        for (int r = 0; r < 4; ++r)
#pragma unroll
            for (int c = 0; c < 8; ++c)
                acc[r][c] = fmaf(xr[r], wc[c], acc[r][c]);
    }

    float a_s[8], a_d[8];
#pragma unroll
    for (int j = 0; j < 8; ++j) { a_s[j] = asrc[cg * 8 + j]; a_d[j] = adst[cg * 8 + j]; }
#pragma unroll
    for (int r = 0; r < 4; ++r) {
        int row = row0 + rg * 4 + r;
        float s1 = 0.f, s2 = 0.f;
#pragma unroll
        for (int j = 0; j < 8; ++j) {
            s1 = fmaf(acc[r][j], a_s[j], s1);
            s2 = fmaf(acc[r][j], a_d[j], s2);
        }
#pragma unroll
        for (int off = 1; off < 8; off <<= 1) {
            s1 += __shfl_xor(s1, off);
            s2 += __shfl_xor(s2, off);
        }
        if (row < N) {
            unsigned int p0 = (unsigned int)f2bf(acc[r][0]) | ((unsigned int)f2bf(acc[r][1]) << 16);
            unsigned int p1 = (unsigned int)f2bf(acc[r][2]) | ((unsigned int)f2bf(acc[r][3]) << 16);
            unsigned int p2 = (unsigned int)f2bf(acc[r][4]) | ((unsigned int)f2bf(acc[r][5]) << 16);
            unsigned int p3 = (unsigned int)f2bf(acc[r][6]) | ((unsigned int)f2bf(acc[r][7]) << 16);
            *(uint4*)&Hb[(size_t)row * 64 + cg * 8] = make_uint4(p0, p1, p2, p3);
            if (cg == 0) { Ss[row] = s1; Sd[row] = s2; }
        }
    }
}

// scatter body: smem needs 3*BMAX ints
__device__ __forceinline__ void scatter_body(
    char* smem, int b, int t,
    const int* __restrict__ src, const int* __restrict__ dst,
    int E0, int N, int B, int per,
    int* __restrict__ gcur, int* __restrict__ part)
{
    int* lh   = (int*)smem;
    int* gb   = lh + BMAX;
    int* lcur = gb + BMAX;
    for (int i = t; i < BMAX; i += 256) lh[i] = 0;
    __syncthreads();
    int Etot = E0 + N;
    int i0 = b * per, i1 = min(Etot, i0 + per);
    for (int i = i0 + t; i < i1; i += 256) {
        int d = (i < E0) ? dst[i] : (i - E0);
        atomicAdd(&lh[d >> 8], 1);
    }
    __syncthreads();
    for (int bin = t; bin < B; bin += 256) {
        int c = lh[bin];
        gb[bin] = c ? atomicAdd(&gcur[bin], c) : 0;
        lcur[bin] = 0;
    }
    __syncthreads();
    for (int i = i0 + t; i < i1; i += 256) {
        int s, d;
        if (i < E0) { s = src[i]; d = dst[i]; } else { s = d = i - E0; }
        int bin = d >> 8;
        int off = atomicAdd(&lcur[bin], 1);
        part[bin * BSTRIDE + gb[bin] + off] = ((d & 255) << 24) | s;  // N < 2^24
    }
}

// K1: heterogeneous — blocks [0,PPART) scatter, rest gemm layer 1 (fp32 X)
__global__ __launch_bounds__(256) void k1_scatter_gemm(
    const int* __restrict__ src, const int* __restrict__ dst,
    int E0, int N, int B, int per,
    int* __restrict__ gcur, int* __restrict__ part,
    const float* __restrict__ X, const float* __restrict__ W,
    const float* __restrict__ asrc, const float* __restrict__ adst,
    unsigned short* __restrict__ Hb, float* __restrict__ Ss, float* __restrict__ Sd)
{
    __shared__ char smem[50176];
    int t = threadIdx.x;
    if (blockIdx.x < PPART)
        scatter_body(smem, blockIdx.x, t, src, dst, E0, N, B, per, gcur, part);
    else
        gemm_body(smem, blockIdx.x - PPART, t, X, 0, W, asrc, adst, Hb, Ss, Sd, N);
}

// layer-2 gemm: bf16 input (A from layer 1)
__global__ __launch_bounds__(256) void gemm_hs_bf16(
    const unsigned short* __restrict__ X, const float* __restrict__ W,
    const float* __restrict__ asrc, const float* __restrict__ adst,
    unsigned short* __restrict__ Hb, float* __restrict__ Ss, float* __restrict__ Sd, int N)
{
    __shared__ char smem[50176];
    gemm_body(smem, blockIdx.x, threadIdx.x, X, 1, W, asrc, adst, Hb, Ss, Sd, N);
}

// ============================================================
// CSR build pass 2: per-bucket counting sort + degree-split lists
// ============================================================
__global__ __launch_bounds__(256) void bucket_sort(
    const int* __restrict__ gcur, const int* __restrict__ part,
    int* __restrict__ ptr, int* __restrict__ csr_src,
    int4* __restrict__ smallL, int4* __restrict__ bigL,
    int* __restrict__ nSmall, int* __restrict__ nBig,
    int N, int B, int Etot)
{
    __shared__ int cnts[256];
    __shared__ int sh[256];
    __shared__ int cur[256];
    __shared__ int sBase, bBase, sCnt, bCnt;
    int t = threadIdx.x, bkt = blockIdx.x;

    int v = 0;
    for (int i = t; i < bkt; i += 256) v += gcur[i];
    sh[t] = v;
    __syncthreads();
    for (int off = 128; off; off >>= 1) {
        if (t < off) sh[t] += sh[t + off];
        __syncthreads();
    }
    int base = sh[0];
    int myCnt = gcur[bkt];
    __syncthreads();

    cnts[t] = 0;
    if (t == 0) { sCnt = 0; bCnt = 0; }
    __syncthreads();
    int pbase = bkt * BSTRIDE;
    for (int i = t; i < myCnt; i += 256)
        atomicAdd(&cnts[((unsigned)part[pbase + i]) >> 24], 1);
    __syncthreads();
    sh[t] = cnts[t];
    __syncthreads();
    for (int off = 1; off < 256; off <<= 1) {
        int x = (t >= off) ? sh[t - off] : 0;
        __syncthreads();
        sh[t] += x;
        __syncthreads();
    }
    int lptr = (t > 0) ? sh[t - 1] : 0;
    int node = bkt * 256 + t;
    int deg = cnts[t];
    int p0 = base + lptr;
    if (node < N) ptr[node] = p0;
    if (bkt == 0 && t == 0) ptr[N] = Etot;
    cur[t] = lptr;
    __syncthreads();
    for (int i = t; i < myCnt; i += 256) {
        int p = part[pbase + i];
        int local = ((unsigned)p) >> 24;
        int s = p & 0xFFFFFF;
        int pos = atomicAdd(&cur[local], 1);
        csr_src[base + pos] = s;
    }

    bool isSm = (node < N) && (deg <= 16);
    bool isBg = (node < N) && (deg > 16);
    int myPos = -1;
    if (isSm) myPos = atomicAdd(&sCnt, 1);
    if (isBg) myPos = atomicAdd(&bCnt, 1);
    __syncthreads();
    if (t == 0) {
        sBase = atomicAdd(nSmall, sCnt);
        bBase = atomicAdd(nBig, bCnt);
    }
    __syncthreads();
    if (isSm) smallL[sBase + myPos] = make_int4(node, p0, deg, 0);
    if (isBg) bigL[bBase + myPos] = make_int4(node, p0, deg, 0);
}

// ============================================================
// Fused aggregation. mode 0: write A (bf16). mode 1: readout dot
// + last-block final reduce (writes out).
// ============================================================
__global__ __launch_bounds__(256) void gat_agg_fused(
    const int4* __restrict__ smallL, const int* __restrict__ nSmallP,
    const int4* __restrict__ bigL, const int* __restrict__ nBigP,
    const int* __restrict__ csr_src,
    const float* __restrict__ Ss, const float* __restrict__ Sd,
    const unsigned short* __restrict__ Hb, const float* __restrict__ bias,
    unsigned short* __restrict__ Ab, const float* __restrict__ Wout,
    float* __restrict__ partials, int* __restrict__ finCnt,
    const float* __restrict__ bout, float* __restrict__ outp, float invN, int mode)
{
    __shared__ float red[256];
    __shared__ int lastBlk;
    int t = threadIdx.x;
    int w = (blockIdx.x * blockDim.x + t) >> 6;
    int lane = t & 63;
    int totWaves = (gridDim.x * blockDim.x) >> 6;
    const ushort4* H4 = (const ushort4*)Hb;
    float dsum = 0.f;

    // ---------- small nodes (deg<=16): 16-lane groups ----------
    {
        int g = lane >> 4;
        int il = lane & 15;
        int gb = lane & 48;
        int nS = *nSmallP;
        float4 bv = ((const float4*)bias)[il];
        float4 wv = ((const float4*)Wout)[il];
        for (int slot0 = w * 4; slot0 < nS; slot0 += totWaves * 4) {
            int slot = slot0 + g;
            int node = -1, p0 = 0, deg = 0;
            if (slot < nS) { int4 e = smallL[slot]; node = e.x; p0 = e.y; deg = e.z; }
            float sdv = (node >= 0) ? Sd[node] : 0.f;
            int s = 0; float e = -INFINITY;
            if (il < deg) {
                s = csr_src[p0 + il];
                float vv = Ss[s] + sdv;
                e = (vv > 0.f) ? vv : NEG_SLOPE * vv;
            }
            float m = e;
#pragma unroll
            for (int off = 8; off; off >>= 1) m = fmaxf(m, __shfl_xor(m, off));
            float ex = (il < deg) ? __expf(e - m) : 0.f;
            float den = ex;
#pragma unroll
            for (int off = 8; off; off >>= 1) den += __shfl_xor(den, off);
            float inv = 1.f / (den + EPS);

            float4 acc = make_float4(0.f, 0.f, 0.f, 0.f);
            for (int j = 0; j < deg; ++j) {
                int   sj = __shfl(s, gb + j);
                float aj = __shfl(ex, gb + j);
                ushort4 hv = H4[(size_t)sj * 16 + il];
                acc.x = fmaf(aj, bf2f(hv.x), acc.x);
                acc.y = fmaf(aj, bf2f(hv.y), acc.y);
                acc.z = fmaf(aj, bf2f(hv.z), acc.z);
                acc.w = fmaf(aj, bf2f(hv.w), acc.w);
            }
            if (node >= 0) {
                float4 o;
                o.x = fmaf(acc.x, inv, bv.x); o.x = (o.x > 0.f) ? o.x : 0.f;
                o.y = fmaf(acc.y, inv, bv.y); o.y = (o.y > 0.f) ? o.y : 0.f;
                o.z = fmaf(acc.z, inv, bv.z); o.z = (o.z > 0.f) ? o.z : 0.f;
                o.w = fmaf(acc.w, inv, bv.w); o.w = (o.w > 0.f) ? o.w : 0.f;
                if (mode == 0) {
                    ushort4 ob;
                    ob.x = f2bf(o.x); ob.y = f2bf(o.y); ob.z = f2bf(o.z); ob.w = f2bf(o.w);
                    ((ushort4*)Ab)[(size_t)node * 16 + il] = ob;
                } else {
                    dsum += o.x * wv.x + o.y * wv.y + o.z * wv.z + o.w * wv.w;
                }
            }
        }
    }

    // ---------- big nodes (deg>16): wave per node, quartered gather ----------
    {
        int q  = lane >> 4;
        int fl = lane & 15;
        int nB = *nBigP;
        for (int slot = w; slot < nB; slot += totWaves) {
            int4 ent = bigL[slot];
            int node = ent.x, p0 = ent.y, deg = ent.z;
            float sdv = Sd[node];
            float4 acc = make_float4(0.f, 0.f, 0.f, 0.f);
            float inv;

            if (deg <= 64) {
                int s = 0; float e = -INFINITY;
                if (lane < deg) {
                    s = csr_src[p0 + lane];
                    float vv = Ss[s] + sdv;
                    e = (vv > 0.f) ? vv : NEG_SLOPE * vv;
                }
                float m = e;
#pragma unroll
                for (int off = 32; off; off >>= 1) m = fmaxf(m, __shfl_xor(m, off));
                float ex = (lane < deg) ? __expf(e - m) : 0.f;
                float den = ex;
#pragma unroll
                for (int off = 32; off; off >>= 1) den += __shfl_xor(den, off);
                inv = 1.f / (den + EPS);
                for (int jb = 0; jb < deg; jb += 4) {
                    int j = jb + q;
                    int   sj = __shfl(s, j);
                    float aj = __shfl(ex, j);
                    ushort4 hv = H4[(size_t)sj * 16 + fl];
                    acc.x = fmaf(aj, bf2f(hv.x), acc.x);
                    acc.y = fmaf(aj, bf2f(hv.y), acc.y);
                    acc.z = fmaf(aj, bf2f(hv.z), acc.z);
                    acc.w = fmaf(aj, bf2f(hv.w), acc.w);
                }
            } else {
                float m = -INFINITY;
                for (int base = 0; base < deg; base += 64) {
                    int idx = base + lane;
                    float e = -INFINITY;
                    if (idx < deg) {
                        int s = csr_src[p0 + idx];
                        float vv = Ss[s] + sdv;
                        e = (vv > 0.f) ? vv : NEG_SLOPE * vv;
                    }
#pragma unroll
                    for (int off = 32; off; off >>= 1) e = fmaxf(e, __shfl_xor(e, off));
                    m = fmaxf(m, e);
                }
                float den = 0.f;
                for (int base = 0; base < deg; base += 64) {
                    int idx = base + lane;
                    float ex = 0.f;
                    if (idx < deg) {
                        int s = csr_src[p0 + idx];
                        float vv = Ss[s] + sdv;
                        float e = (vv > 0.f) ? vv : NEG_SLOPE * vv;
                        ex = __expf(e - m);
                    }
#pragma unroll
                    for (int off = 32; off; off >>= 1) ex += __shfl_xor(ex, off);
                    den += ex;
                }
                inv = 1.f / (den + EPS);
                for (int base = 0; base < deg; base += 64) {
                    int idx = base + lane;
                    int s = 0; float ex = 0.f;
                    if (idx < deg) {
                        s = csr_src[p0 + idx];
                        float vv = Ss[s] + sdv;
                        float e = (vv > 0.f) ? vv : NEG_SLOPE * vv;
                        ex = __expf(e - m);
                    }
                    int cnt = min(64, deg - base);
                    for (int jb = 0; jb < cnt; jb += 4) {
                        int j = jb + q;
                        int   sj = __shfl(s, j);
                        float aj = __shfl(ex, j);
                        ushort4 hv = H4[(size_t)sj * 16 + fl];
                        acc.x = fmaf(aj, bf2f(hv.x), acc.x);
                        acc.y = fmaf(aj, bf2f(hv.y), acc.y);
                        acc.z = fmaf(aj, bf2f(hv.z), acc.z);
                        acc.w = fmaf(aj, bf2f(hv.w), acc.w);
                    }
                }
            }

#pragma unroll
            for (int off = 16; off < 64; off <<= 1) {
                acc.x += __shfl_xor(acc.x, off);
                acc.y += __shfl_xor(acc.y, off);
                acc.z += __shfl_xor(acc.z, off);
                acc.w += __shfl_xor(acc.w, off);
            }
            if (q == 0) {
                float4 bv = ((const float4*)bias)[fl];
                float4 o;
                o.x = fmaf(acc.x, inv, bv.x); o.x = (o.x > 0.f) ? o.x : 0.f;
                o.y = fmaf(acc.y, inv, bv.y); o.y = (o.y > 0.f) ? o.y : 0.f;
                o.z = fmaf(acc.z, inv, bv.z); o.z = (o.z > 0.f) ? o.z : 0.f;
                o.w = fmaf(acc.w, inv, bv.w); o.w = (o.w > 0.f) ? o.w : 0.f;
                if (mode == 0) {
                    ushort4 ob;
                    ob.x = f2bf(o.x); ob.y = f2bf(o.y); ob.z = f2bf(o.z); ob.w = f2bf(o.w);
                    ((ushort4*)Ab)[(size_t)node * 16 + fl] = ob;
                } else {
                    float4 wv = ((const float4*)Wout)[fl];
                    dsum += o.x * wv.x + o.y * wv.y + o.z * wv.z + o.w * wv.w;
                }
            }
        }
    }

    if (mode == 1) {
        red[t] = dsum;
        __syncthreads();
        for (int off = 128; off; off >>= 1) {
            if (t < off) red[t] += red[t + off];
            __syncthreads();
        }
        if (t == 0) {
            partials[blockIdx.x] = red[0];
            __threadfence();
            int old = atomicAdd(finCnt, 1);
            lastBlk = (old == (int)gridDim.x - 1);
        }
        __syncthreads();
        if (lastBlk) {
            float s = 0.f;
            for (int i = t; i < (int)gridDim.x; i += 256) s += partials[i];
            red[t] = s;
            __syncthreads();
            for (int off = 128; off; off >>= 1) {
                if (t < off) red[t] += red[t + off];
                __syncthreads();
            }
            if (t == 0) outp[0] = fmaf(red[0], invN, bout[0]);
        }
    }
}

extern "C" void kernel_launch(void* const* d_in, const int* in_sizes, int n_in,
                              void* d_out, int out_size, void* d_ws, size_t ws_size,
                              hipStream_t stream)
{
    const float* x    = (const float*)d_in[0];
    const int*   ei   = (const int*)d_in[1];
    const float* W1   = (const float*)d_in[2];
    const float* as1  = (const float*)d_in[3];
    const float* ad1  = (const float*)d_in[4];
    const float* b1   = (const float*)d_in[5];
    const float* W2   = (const float*)d_in[6];
    const float* as2  = (const float*)d_in[7];
    const float* ad2  = (const float*)d_in[8];
    const float* b2   = (const float*)d_in[9];
    const float* Wout = (const float*)d_in[10];
    const float* bout = (const float*)d_in[11];
    float* out = (float*)d_out;

    int N    = in_sizes[0] / 64;
    int E0   = in_sizes[1] / 2;
    int Etot = E0 + N;
    const int* srcp = ei;
    const int* dstp = ei + E0;

    int B   = (N + 255) >> 8;
    int per = (Etot + PPART - 1) / PPART;

    // ---- workspace layout ----
    unsigned short* Hb = (unsigned short*)d_ws;         // N*64 bf16
    unsigned short* Ab = Hb + (size_t)N * 64;           // N*64 bf16
    float* Ss  = (float*)(Ab + (size_t)N * 64);         // N
    float* Sd  = Ss + N;                                // N
    int* ptr   = (int*)(Sd + N);                        // N+1
    int* gcur  = ptr + N + 1;                           // 512
    int* nSmall = gcur + 512;                           // 1
    int* nBig   = nSmall + 1;                           // 1
    int* finCnt = nBig + 1;                             // 1
    int* part  = finCnt + 1;                            // B*BSTRIDE
    int* csr_src = part + (size_t)B * BSTRIDE;          // Etot
    int4* smallL = (int4*)(csr_src + Etot);             // N
    int4* bigL   = smallL + N;                          // N
    float* partials = (float*)(bigL + N);               // GAGG_BLOCKS

    int gGemm = (N + 127) / 128;

    // K0: zero cursors/counters
    hipMemsetAsync(gcur, 0, (512 + 3) * sizeof(int), stream);

    // K1: CSR scatter || layer-1 GEMM (fp32 X)
    k1_scatter_gemm<<<PPART + gGemm, 256, 0, stream>>>(
        srcp, dstp, E0, N, B, per, gcur, part,
        x, W1, as1, ad1, Hb, Ss, Sd);

    // K2: CSR pass 2
    bucket_sort<<<B, 256, 0, stream>>>(gcur, part, ptr, csr_src, smallL, bigL,
                                       nSmall, nBig, N, B, Etot);

    // K3: layer-1 aggregation (writes bf16 A)
    gat_agg_fused<<<GAGG_BLOCKS, 256, 0, stream>>>(
        smallL, nSmall, bigL, nBig, csr_src, Ss, Sd, Hb, b1, Ab, Wout,
        partials, finCnt, bout, out, 1.0f / (float)N, 0);

    // K4: layer-2 GEMM (bf16 A input)
    gemm_hs_bf16<<<gGemm, 256, 0, stream>>>(Ab, W2, as2, ad2, Hb, Ss, Sd, N);

    // K5: layer-2 aggregation + fused readout + final reduce
    gat_agg_fused<<<GAGG_BLOCKS, 256, 0, stream>>>(
        smallL, nSmall, bigL, nBig, csr_src, Ss, Sd, Hb, b2, Ab, Wout,
        partials, finCnt, bout, out, 1.0f / (float)N, 1);
}

// Round 11
// 238.102 us; speedup vs baseline: 1.1746x; 1.1746x over previous
//
#include <hip/hip_runtime.h>
#include <math.h>

#define NEG_SLOPE 0.2f
#define EPS 1e-16f
#define PPART 256          // scatter blocks (in hetero K1)
#define BMAX 512           // max buckets (B = ceil(N/256) = 391)
#define BSTRIDE 6144       // part[] slots per bucket (max bucket ~3.7k)
#define GAGG_BLOCKS 2048   // agg kernel grid

// ---- bf16 helpers ----
__device__ __forceinline__ unsigned short f2bf(float f) {
    unsigned int x = __float_as_uint(f);
    unsigned int r = (x + 0x7FFFu + ((x >> 16) & 1u)) >> 16;
    return (unsigned short)r;
}
__device__ __forceinline__ float bf2f(unsigned short u) {
    return __uint_as_float(((unsigned int)u) << 16);
}

// ============================================================
// GEMM body: H(bf16) = X @ W ; Ss = H.a_src, Sd = H.a_dst.
// X is fp32 (xbf16=0) or bf16 (xbf16=1).
// smem: Ws 4096 f + Xs 64*XPAD f (50176 B)
// ============================================================
#define XPAD 132
__device__ __forceinline__ void gemm_body(
    char* smem, int bid, int t,
    const void* __restrict__ Xv, int xbf16, const float* __restrict__ W,
    const float* __restrict__ asrc, const float* __restrict__ adst,
    unsigned short* __restrict__ Hb, float* __restrict__ Ss, float* __restrict__ Sd, int N)
{
    float* Ws = (float*)smem;            // 64*64
    float* Xs = Ws + 4096;               // 64*XPAD
    int row0 = bid * 128;

    {
        const float4* W4 = (const float4*)W;
        float4* Ws4 = (float4*)Ws;
#pragma unroll
        for (int i = 0; i < 4; ++i) Ws4[i * 256 + t] = W4[i * 256 + t];
    }
    if (!xbf16) {
        const float4* X4 = (const float4*)Xv;
#pragma unroll
        for (int i = 0; i < 8; ++i) {
            int v = i * 256 + t;
            int r = v >> 4;
            int c4 = (v & 15) * 4;
            int grow = row0 + r;
            float4 xv = make_float4(0.f, 0.f, 0.f, 0.f);
            if (grow < N) xv = X4[(size_t)grow * 16 + (c4 >> 2)];
            Xs[(c4 + 0) * XPAD + r] = xv.x;
            Xs[(c4 + 1) * XPAD + r] = xv.y;
            Xs[(c4 + 2) * XPAD + r] = xv.z;
            Xs[(c4 + 3) * XPAD + r] = xv.w;
        }
    } else {
        const uint4* X4 = (const uint4*)Xv;   // 8 bf16 per uint4; row = 8 uint4
#pragma unroll
        for (int i = 0; i < 4; ++i) {
            int v = i * 256 + t;
            int r = v >> 3;                   // 0..127
            int c8 = (v & 7) * 8;             // 0,8,...,56
            int grow = row0 + r;
            uint4 xv = make_uint4(0, 0, 0, 0);
            if (grow < N) xv = X4[(size_t)grow * 8 + (c8 >> 3)];
            Xs[(c8 + 0) * XPAD + r] = bf2f((unsigned short)(xv.x & 0xFFFF));
            Xs[(c8 + 1) * XPAD + r] = bf2f((unsigned short)(xv.x >> 16));
            Xs[(c8 + 2) * XPAD + r] = bf2f((unsigned short)(xv.y & 0xFFFF));
            Xs[(c8 + 3) * XPAD + r] = bf2f((unsigned short)(xv.y >> 16));
            Xs[(c8 + 4) * XPAD + r] = bf2f((unsigned short)(xv.z & 0xFFFF));
            Xs[(c8 + 5) * XPAD + r] = bf2f((unsigned short)(xv.z >> 16));
            Xs[(c8 + 6) * XPAD + r] = bf2f((unsigned short)(xv.w & 0xFFFF));
            Xs[(c8 + 7) * XPAD + r] = bf2f((unsigned short)(xv.w >> 16));
        }
    }
    __syncthreads();

    int cg = t & 7;
    int rg = t >> 3;
    float acc[4][8] = {{0.f}};

#pragma unroll 8
    for (int k = 0; k < 64; ++k) {
        float4 xv = *(const float4*)&Xs[k * XPAD + rg * 4];
        float4 w0 = *(const float4*)&Ws[k * 64 + cg * 8];
        float4 w1 = *(const float4*)&Ws[k * 64 + cg * 8 + 4];
        float xr[4] = {xv.x, xv.y, xv.z, xv.w};
        float wc[8] = {w0.x, w0.y, w0.z, w0.w, w1.x, w1.y, w1.z, w1.w};
#pragma unroll
        for (int r = 0; r < 4; ++r)
#pragma unroll
            for (int c = 0; c < 8; ++c)
                acc[r][c] = fmaf(xr[r], wc[c], acc[r][c]);
    }

    float a_s[8], a_d[8];
#pragma unroll
    for (int j = 0; j < 8; ++j) { a_s[j] = asrc[cg * 8 + j]; a_d[j] = adst[cg * 8 + j]; }
#pragma unroll
    for (int r = 0; r < 4; ++r) {
        int row = row0 + rg * 4 + r;
        float s1 = 0.f, s2 = 0.f;
#pragma unroll
        for (int j = 0; j < 8; ++j) {
            s1 = fmaf(acc[r][j], a_s[j], s1);
            s2 = fmaf(acc[r][j], a_d[j], s2);
        }
#pragma unroll
        for (int off = 1; off < 8; off <<= 1) {
            s1 += __shfl_xor(s1, off);
            s2 += __shfl_xor(s2, off);
        }
        if (row < N) {
            unsigned int p0 = (unsigned int)f2bf(acc[r][0]) | ((unsigned int)f2bf(acc[r][1]) << 16);
            unsigned int p1 = (unsigned int)f2bf(acc[r][2]) | ((unsigned int)f2bf(acc[r][3]) << 16);
            unsigned int p2 = (unsigned int)f2bf(acc[r][4]) | ((unsigned int)f2bf(acc[r][5]) << 16);
            unsigned int p3 = (unsigned int)f2bf(acc[r][6]) | ((unsigned int)f2bf(acc[r][7]) << 16);
            *(uint4*)&Hb[(size_t)row * 64 + cg * 8] = make_uint4(p0, p1, p2, p3);
            if (cg == 0) { Ss[row] = s1; Sd[row] = s2; }
        }
    }
}

// scatter body: smem needs 3*BMAX ints
__device__ __forceinline__ void scatter_body(
    char* smem, int b, int t,
    const int* __restrict__ src, const int* __restrict__ dst,
    int E0, int N, int B, int per,
    int* __restrict__ gcur, int* __restrict__ part)
{
    int* lh   = (int*)smem;
    int* gb   = lh + BMAX;
    int* lcur = gb + BMAX;
    for (int i = t; i < BMAX; i += 256) lh[i] = 0;
    __syncthreads();
    int Etot = E0 + N;
    int i0 = b * per, i1 = min(Etot, i0 + per);
    for (int i = i0 + t; i < i1; i += 256) {
        int d = (i < E0) ? dst[i] : (i - E0);
        atomicAdd(&lh[d >> 8], 1);
    }
    __syncthreads();
    for (int bin = t; bin < B; bin += 256) {
        int c = lh[bin];
        gb[bin] = c ? atomicAdd(&gcur[bin], c) : 0;
        lcur[bin] = 0;
    }
    __syncthreads();
    for (int i = i0 + t; i < i1; i += 256) {
        int s, d;
        if (i < E0) { s = src[i]; d = dst[i]; } else { s = d = i - E0; }
        int bin = d >> 8;
        int off = atomicAdd(&lcur[bin], 1);
        part[bin * BSTRIDE + gb[bin] + off] = ((d & 255) << 24) | s;  // N < 2^24
    }
}

// K1: heterogeneous — blocks [0,PPART) scatter, rest gemm layer 1 (fp32 X)
__global__ __launch_bounds__(256) void k1_scatter_gemm(
    const int* __restrict__ src, const int* __restrict__ dst,
    int E0, int N, int B, int per,
    int* __restrict__ gcur, int* __restrict__ part,
    const float* __restrict__ X, const float* __restrict__ W,
    const float* __restrict__ asrc, const float* __restrict__ adst,
    unsigned short* __restrict__ Hb, float* __restrict__ Ss, float* __restrict__ Sd)
{
    __shared__ char smem[50176];
    int t = threadIdx.x;
    if (blockIdx.x < PPART)
        scatter_body(smem, blockIdx.x, t, src, dst, E0, N, B, per, gcur, part);
    else
        gemm_body(smem, blockIdx.x - PPART, t, X, 0, W, asrc, adst, Hb, Ss, Sd, N);
}

// layer-2 gemm: bf16 input (A from layer 1)
__global__ __launch_bounds__(256) void gemm_hs_bf16(
    const unsigned short* __restrict__ X, const float* __restrict__ W,
    const float* __restrict__ asrc, const float* __restrict__ adst,
    unsigned short* __restrict__ Hb, float* __restrict__ Ss, float* __restrict__ Sd, int N)
{
    __shared__ char smem[50176];
    gemm_body(smem, blockIdx.x, threadIdx.x, X, 1, W, asrc, adst, Hb, Ss, Sd, N);
}

// ============================================================
// CSR build pass 2: per-bucket counting sort + degree-split lists
// ============================================================
__global__ __launch_bounds__(256) void bucket_sort(
    const int* __restrict__ gcur, const int* __restrict__ part,
    int* __restrict__ ptr, int* __restrict__ csr_src,
    int4* __restrict__ smallL, int4* __restrict__ bigL,
    int* __restrict__ nSmall, int* __restrict__ nBig,
    int N, int B, int Etot)
{
    __shared__ int cnts[256];
    __shared__ int sh[256];
    __shared__ int cur[256];
    __shared__ int sBase, bBase, sCnt, bCnt;
    int t = threadIdx.x, bkt = blockIdx.x;

    int v = 0;
    for (int i = t; i < bkt; i += 256) v += gcur[i];
    sh[t] = v;
    __syncthreads();
    for (int off = 128; off; off >>= 1) {
        if (t < off) sh[t] += sh[t + off];
        __syncthreads();
    }
    int base = sh[0];
    int myCnt = gcur[bkt];
    __syncthreads();

    cnts[t] = 0;
    if (t == 0) { sCnt = 0; bCnt = 0; }
    __syncthreads();
    int pbase = bkt * BSTRIDE;
    for (int i = t; i < myCnt; i += 256)
        atomicAdd(&cnts[((unsigned)part[pbase + i]) >> 24], 1);
    __syncthreads();
    sh[t] = cnts[t];
    __syncthreads();
    for (int off = 1; off < 256; off <<= 1) {
        int x = (t >= off) ? sh[t - off] : 0;
        __syncthreads();
        sh[t] += x;
        __syncthreads();
    }
    int lptr = (t > 0) ? sh[t - 1] : 0;
    int node = bkt * 256 + t;
    int deg = cnts[t];
    int p0 = base + lptr;
    if (node < N) ptr[node] = p0;
    if (bkt == 0 && t == 0) ptr[N] = Etot;
    cur[t] = lptr;
    __syncthreads();
    for (int i = t; i < myCnt; i += 256) {
        int p = part[pbase + i];
        int local = ((unsigned)p) >> 24;
        int s = p & 0xFFFFFF;
        int pos = atomicAdd(&cur[local], 1);
        csr_src[base + pos] = s;
    }

    bool isSm = (node < N) && (deg <= 16);
    bool isBg = (node < N) && (deg > 16);
    int myPos = -1;
    if (isSm) myPos = atomicAdd(&sCnt, 1);
    if (isBg) myPos = atomicAdd(&bCnt, 1);
    __syncthreads();
    if (t == 0) {
        sBase = atomicAdd(nSmall, sCnt);
        bBase = atomicAdd(nBig, bCnt);
    }
    __syncthreads();
    if (isSm) smallL[sBase + myPos] = make_int4(node, p0, deg, 0);
    if (isBg) bigL[bBase + myPos] = make_int4(node, p0, deg, 0);
}

// ============================================================
// Fused aggregation. mode 0: write A (bf16). mode 1: readout dot
// into per-block partials (no fence — separate final_reduce kernel).
// ============================================================
__global__ __launch_bounds__(256) void gat_agg_fused(
    const int4* __restrict__ smallL, const int* __restrict__ nSmallP,
    const int4* __restrict__ bigL, const int* __restrict__ nBigP,
    const int* __restrict__ csr_src,
    const float* __restrict__ Ss, const float* __restrict__ Sd,
    const unsigned short* __restrict__ Hb, const float* __restrict__ bias,
    unsigned short* __restrict__ Ab, const float* __restrict__ Wout,
    float* __restrict__ partials, int mode)
{
    __shared__ float red[256];
    int t = threadIdx.x;
    int w = (blockIdx.x * blockDim.x + t) >> 6;
    int lane = t & 63;
    int totWaves = (gridDim.x * blockDim.x) >> 6;
    const ushort4* H4 = (const ushort4*)Hb;
    float dsum = 0.f;

    // ---------- small nodes (deg<=16): 16-lane groups ----------
    {
        int g = lane >> 4;
        int il = lane & 15;
        int gb = lane & 48;
        int nS = *nSmallP;
        float4 bv = ((const float4*)bias)[il];
        float4 wv = ((const float4*)Wout)[il];
        for (int slot0 = w * 4; slot0 < nS; slot0 += totWaves * 4) {
            int slot = slot0 + g;
            int node = -1, p0 = 0, deg = 0;
            if (slot < nS) { int4 e = smallL[slot]; node = e.x; p0 = e.y; deg = e.z; }
            float sdv = (node >= 0) ? Sd[node] : 0.f;
            int s = 0; float e = -INFINITY;
            if (il < deg) {
                s = csr_src[p0 + il];
                float vv = Ss[s] + sdv;
                e = (vv > 0.f) ? vv : NEG_SLOPE * vv;
            }
            float m = e;
#pragma unroll
            for (int off = 8; off; off >>= 1) m = fmaxf(m, __shfl_xor(m, off));
            float ex = (il < deg) ? __expf(e - m) : 0.f;
            float den = ex;
#pragma unroll
            for (int off = 8; off; off >>= 1) den += __shfl_xor(den, off);
            float inv = 1.f / (den + EPS);

            float4 acc = make_float4(0.f, 0.f, 0.f, 0.f);
            for (int j = 0; j < deg; ++j) {
                int   sj = __shfl(s, gb + j);
                float aj = __shfl(ex, gb + j);
                ushort4 hv = H4[(size_t)sj * 16 + il];
                acc.x = fmaf(aj, bf2f(hv.x), acc.x);
                acc.y = fmaf(aj, bf2f(hv.y), acc.y);
                acc.z = fmaf(aj, bf2f(hv.z), acc.z);
                acc.w = fmaf(aj, bf2f(hv.w), acc.w);
            }
            if (node >= 0) {
                float4 o;
                o.x = fmaf(acc.x, inv, bv.x); o.x = (o.x > 0.f) ? o.x : 0.f;
                o.y = fmaf(acc.y, inv, bv.y); o.y = (o.y > 0.f) ? o.y : 0.f;
                o.z = fmaf(acc.z, inv, bv.z); o.z = (o.z > 0.f) ? o.z : 0.f;
                o.w = fmaf(acc.w, inv, bv.w); o.w = (o.w > 0.f) ? o.w : 0.f;
                if (mode == 0) {
                    ushort4 ob;
                    ob.x = f2bf(o.x); ob.y = f2bf(o.y); ob.z = f2bf(o.z); ob.w = f2bf(o.w);
                    ((ushort4*)Ab)[(size_t)node * 16 + il] = ob;
                } else {
                    dsum += o.x * wv.x + o.y * wv.y + o.z * wv.z + o.w * wv.w;
                }
            }
        }
    }

    // ---------- big nodes (deg>16): wave per node, quartered gather ----------
    {
        int q  = lane >> 4;
        int fl = lane & 15;
        int nB = *nBigP;
        for (int slot = w; slot < nB; slot += totWaves) {
            int4 ent = bigL[slot];
            int node = ent.x, p0 = ent.y, deg = ent.z;
            float sdv = Sd[node];
            float4 acc = make_float4(0.f, 0.f, 0.f, 0.f);
            float inv;

            if (deg <= 64) {
                int s = 0; float e = -INFINITY;
                if (lane < deg) {
                    s = csr_src[p0 + lane];
                    float vv = Ss[s] + sdv;
                    e = (vv > 0.f) ? vv : NEG_SLOPE * vv;
                }
                float m = e;
#pragma unroll
                for (int off = 32; off; off >>= 1) m = fmaxf(m, __shfl_xor(m, off));
                float ex = (lane < deg) ? __expf(e - m) : 0.f;
                float den = ex;
#pragma unroll
                for (int off = 32; off; off >>= 1) den += __shfl_xor(den, off);
                inv = 1.f / (den + EPS);
                for (int jb = 0; jb < deg; jb += 4) {
                    int j = jb + q;
                    int   sj = __shfl(s, j);
                    float aj = __shfl(ex, j);
                    ushort4 hv = H4[(size_t)sj * 16 + fl];
                    acc.x = fmaf(aj, bf2f(hv.x), acc.x);
                    acc.y = fmaf(aj, bf2f(hv.y), acc.y);
                    acc.z = fmaf(aj, bf2f(hv.z), acc.z);
                    acc.w = fmaf(aj, bf2f(hv.w), acc.w);
                }
            } else {
                float m = -INFINITY;
                for (int base = 0; base < deg; base += 64) {
                    int idx = base + lane;
                    float e = -INFINITY;
                    if (idx < deg) {
                        int s = csr_src[p0 + idx];
                        float vv = Ss[s] + sdv;
                        e = (vv > 0.f) ? vv : NEG_SLOPE * vv;
                    }
#pragma unroll
                    for (int off = 32; off; off >>= 1) e = fmaxf(e, __shfl_xor(e, off));
                    m = fmaxf(m, e);
                }
                float den = 0.f;
                for (int base = 0; base < deg; base += 64) {
                    int idx = base + lane;
                    float ex = 0.f;
                    if (idx < deg) {
                        int s = csr_src[p0 + idx];
                        float vv = Ss[s] + sdv;
                        float e = (vv > 0.f) ? vv : NEG_SLOPE * vv;
                        ex = __expf(e - m);
                    }
#pragma unroll
                    for (int off = 32; off; off >>= 1) ex += __shfl_xor(ex, off);
                    den += ex;
                }
                inv = 1.f / (den + EPS);
                for (int base = 0; base < deg; base += 64) {
                    int idx = base + lane;
                    int s = 0; float ex = 0.f;
                    if (idx < deg) {
                        s = csr_src[p0 + idx];
                        float vv = Ss[s] + sdv;
                        float e = (vv > 0.f) ? vv : NEG_SLOPE * vv;
                        ex = __expf(e - m);
                    }
                    int cnt = min(64, deg - base);
                    for (int jb = 0; jb < cnt; jb += 4) {
                        int j = jb + q;
                        int   sj = __shfl(s, j);
                        float aj = __shfl(ex, j);
                        ushort4 hv = H4[(size_t)sj * 16 + fl];
                        acc.x = fmaf(aj, bf2f(hv.x), acc.x);
                        acc.y = fmaf(aj, bf2f(hv.y), acc.y);
                        acc.z = fmaf(aj, bf2f(hv.z), acc.z);
                        acc.w = fmaf(aj, bf2f(hv.w), acc.w);
                    }
                }
            }

#pragma unroll
            for (int off = 16; off < 64; off <<= 1) {
                acc.x += __shfl_xor(acc.x, off);
                acc.y += __shfl_xor(acc.y, off);
                acc.z += __shfl_xor(acc.z, off);
                acc.w += __shfl_xor(acc.w, off);
            }
            if (q == 0) {
                float4 bv = ((const float4*)bias)[fl];
                float4 o;
                o.x = fmaf(acc.x, inv, bv.x); o.x = (o.x > 0.f) ? o.x : 0.f;
                o.y = fmaf(acc.y, inv, bv.y); o.y = (o.y > 0.f) ? o.y : 0.f;
                o.z = fmaf(acc.z, inv, bv.z); o.z = (o.z > 0.f) ? o.z : 0.f;
                o.w = fmaf(acc.w, inv, bv.w); o.w = (o.w > 0.f) ? o.w : 0.f;
                if (mode == 0) {
                    ushort4 ob;
                    ob.x = f2bf(o.x); ob.y = f2bf(o.y); ob.z = f2bf(o.z); ob.w = f2bf(o.w);
                    ((ushort4*)Ab)[(size_t)node * 16 + fl] = ob;
                } else {
                    float4 wv = ((const float4*)Wout)[fl];
                    dsum += o.x * wv.x + o.y * wv.y + o.z * wv.z + o.w * wv.w;
                }
            }
        }
    }

    if (mode == 1) {
        red[t] = dsum;
        __syncthreads();
        for (int off = 128; off; off >>= 1) {
            if (t < off) red[t] += red[t + off];
            __syncthreads();
        }
        if (t == 0) partials[blockIdx.x] = red[0];
    }
}

// final: out = (sum partials)/N + bout
__global__ __launch_bounds__(256) void final_reduce(
    const float* __restrict__ partials, int np,
    const float* __restrict__ bout, float* __restrict__ out, float invN)
{
    __shared__ float red[256];
    int t = threadIdx.x;
    float s = 0.f;
    for (int i = t; i < np; i += 256) s += partials[i];
    red[t] = s;
    __syncthreads();
    for (int off = 128; off; off >>= 1) {
        if (t < off) red[t] += red[t + off];
        __syncthreads();
    }
    if (t == 0) out[0] = fmaf(red[0], invN, bout[0]);
}

extern "C" void kernel_launch(void* const* d_in, const int* in_sizes, int n_in,
                              void* d_out, int out_size, void* d_ws, size_t ws_size,
                              hipStream_t stream)
{
    const float* x    = (const float*)d_in[0];
    const int*   ei   = (const int*)d_in[1];
    const float* W1   = (const float*)d_in[2];
    const float* as1  = (const float*)d_in[3];
    const float* ad1  = (const float*)d_in[4];
    const float* b1   = (const float*)d_in[5];
    const float* W2   = (const float*)d_in[6];
    const float* as2  = (const float*)d_in[7];
    const float* ad2  = (const float*)d_in[8];
    const float* b2   = (const float*)d_in[9];
    const float* Wout = (const float*)d_in[10];
    const float* bout = (const float*)d_in[11];
    float* out = (float*)d_out;

    int N    = in_sizes[0] / 64;
    int E0   = in_sizes[1] / 2;
    int Etot = E0 + N;
    const int* srcp = ei;
    const int* dstp = ei + E0;

    int B   = (N + 255) >> 8;
    int per = (Etot + PPART - 1) / PPART;

    // ---- workspace layout ----
    unsigned short* Hb = (unsigned short*)d_ws;         // N*64 bf16
    unsigned short* Ab = Hb + (size_t)N * 64;           // N*64 bf16
    float* Ss  = (float*)(Ab + (size_t)N * 64);         // N
    float* Sd  = Ss + N;                                // N
    int* ptr   = (int*)(Sd + N);                        // N+1
    int* gcur  = ptr + N + 1;                           // 512
    int* nSmall = gcur + 512;                           // 1
    int* nBig   = nSmall + 1;                           // 1
    int* part  = nBig + 1;                              // B*BSTRIDE
    int* csr_src = part + (size_t)B * BSTRIDE;          // Etot
    int4* smallL = (int4*)(csr_src + Etot);             // N
    int4* bigL   = smallL + N;                          // N
    float* partials = (float*)(bigL + N);               // GAGG_BLOCKS

    int gGemm = (N + 127) / 128;

    // K0: zero cursors/counters
    hipMemsetAsync(gcur, 0, (512 + 2) * sizeof(int), stream);

    // K1: CSR scatter || layer-1 GEMM (fp32 X)
    k1_scatter_gemm<<<PPART + gGemm, 256, 0, stream>>>(
        srcp, dstp, E0, N, B, per, gcur, part,
        x, W1, as1, ad1, Hb, Ss, Sd);

    // K2: CSR pass 2
    bucket_sort<<<B, 256, 0, stream>>>(gcur, part, ptr, csr_src, smallL, bigL,
                                       nSmall, nBig, N, B, Etot);

    // K3: layer-1 aggregation (writes bf16 A)
    gat_agg_fused<<<GAGG_BLOCKS, 256, 0, stream>>>(
        smallL, nSmall, bigL, nBig, csr_src, Ss, Sd, Hb, b1, Ab, Wout, partials, 0);

    // K4: layer-2 GEMM (bf16 A input)
    gemm_hs_bf16<<<gGemm, 256, 0, stream>>>(Ab, W2, as2, ad2, Hb, Ss, Sd, N);

    // K5: layer-2 aggregation + fused readout dot
    gat_agg_fused<<<GAGG_BLOCKS, 256, 0, stream>>>(
        smallL, nSmall, bigL, nBig, csr_src, Ss, Sd, Hb, b2, Ab, Wout, partials, 1);

    // K6: final reduce
    final_reduce<<<1, 256, 0, stream>>>(partials, GAGG_BLOCKS, bout, out, 1.0f / (float)N);
}